// Round 1
// baseline (2242.321 us; speedup 1.0000x reference)
//
#include <hip/hip_runtime.h>

// DTW accumulated-cost, output = last column. N=65536 rows (input), K=512 cols (kernel).
// Anti-diagonal recurrence, 4 waves (one per SIMD), j = 128*w + 2*lane + slot,
// skewed-chunk barrier pipeline passing band-boundary E values through LDS rings.
//
// R3: memory-free inner loop. R2's xv[64]/binv[64]/keep[64] "register arrays" never
// became registers (VGPR_Count=52 => rolled loops + scratch, rule #20). Replaced by:
//  - binv: ONE ds_read_b32/chunk into a DPP shift register (lane r holds binv[r];
//    wave_shl:1 each iter so lane0's dpp-`old` is binv[r] at iter r)
//  - keep: DPP insert register (wave_shl:1 inserts lane63's E at lane63 each iter;
//    after 64 iters lane r holds keep[r]) -> ONE ds_write_b32/chunk
//    (wave 3: one direct coalesced global store, no LDS staging)
//  - x: double-buffered float2 register blocks (8B-aligned; j0 even), 16-iter prefetch
//  - slot1 min3: E0(r-1) = min(A0(r-1), A0(r-2)) so na1 = min3(A1,A0,A0p)+d1 (E0 gone)
//  - barrier = asm "s_waitcnt lgkmcnt(0); s_barrier": only the LDS publish must drain;
//    __syncthreads' vmcnt(0) was serializing wave3's global stores into every barrier.

#define K_LEN 512
#define N_LEN 65536
#define PAD_L 512
#define PAD_R 1024
#define XPAD_TOTAL (PAD_L + N_LEN + PAD_R) // 67072 floats = 268288 B of d_ws
#define BIGX 1e20f
#define NCHUNK 1032                        // 1032*64 = 66048 >= N+K-1 = 66047 diagonals
#define RING 256                           // ring entries per boundary buffer (4 chunks)

typedef float f32x2 __attribute__((ext_vector_type(2)));

__global__ void dtw_pad_kernel(const float* __restrict__ x, float* __restrict__ xpad) {
    int i = blockIdx.x * blockDim.x + threadIdx.x;
    if (i < XPAD_TOTAL) {
        int j = i - PAD_L;
        xpad[i] = (j >= 0 && j < N_LEN) ? x[j] : BIGX;
    }
}

// lane l <- lane l-1 of src; lane 0 <- old[0]        (wave_shr:1, bound_ctrl=0)
__device__ __forceinline__ float dpp_wave_shr1(float oldv, float src) {
    return __int_as_float(__builtin_amdgcn_update_dpp(
        __float_as_int(oldv), __float_as_int(src), 0x138, 0xF, 0xF, false));
}
// lane l <- lane l+1 of src; lane 63 <- old[63]      (wave_shl:1, bound_ctrl=0)
__device__ __forceinline__ float dpp_wave_shl1(float oldv, float src) {
    return __int_as_float(__builtin_amdgcn_update_dpp(
        __float_as_int(oldv), __float_as_int(src), 0x130, 0xF, 0xF, false));
}

template <bool LAST>
__device__ __forceinline__ void dtw_chunk(int c, const float* __restrict__ xl,
                                          const float* __restrict__ ldsIn,
                                          float* __restrict__ ldsOut,
                                          float k0, float k1,
                                          float& A0, float& A0p, float& A1, float& E1,
                                          float& xp, int lane, float* __restrict__ out) {
    const int t0 = c * 64;
    const int rb = (c & 3) * 64;

    // One-shot boundary read: lane r <- binv[r] = producer E at diagonal t0+r-1.
    // r=0 wraps to previous chunk's last entry ((-1)&255 == 255). Consecutive
    // addresses -> 2 lanes/bank, conflict-free.
    float binvreg = ldsIn[(rb + lane - 1) & (RING - 1)];
    float keepreg = 0.0f; // fully overwritten by 64 inserts

    const f32x2* __restrict__ xl2 = (const f32x2*)(xl + t0); // even float offset -> 8B aligned

    auto ITER = [&](float xf) {
        // slot0 shifted E: lane l <- lane l-1's E1; lane 0 <- binvreg[0] (= binv[r])
        const float esh0 = dpp_wave_shr1(binvreg, E1);
        binvreg = dpp_wave_shl1(binvreg, binvreg); // advance: lane0 <- binv[r+1]
        const float t0v = k0 - xf;
        const float na0 = __builtin_fmaf(t0v, t0v, fminf(A0, esh0));
        const float t1v = k1 - xp;
        const float m1  = fminf(A0p, fminf(A1, A0)); // = min(A1, E0_prev), E0 eliminated
        const float na1 = __builtin_fmaf(t1v, t1v, m1);
        const float ne1 = fminf(na1, A1);
        // collect lane63's boundary value (wave3: column-511 output) at lane63,
        // shifting down: after 64 iters lane r holds the iter-r value
        keepreg = dpp_wave_shl1(LAST ? na1 : ne1, keepreg);
        A0p = A0; A0 = na0; A1 = na1; E1 = ne1; xp = xf;
    };

    auto LOAD8 = [&](f32x2 (&X)[8], int base) {
#pragma unroll
        for (int q = 0; q < 8; ++q) X[q] = xl2[base + q];
    };
    auto BLOCK16 = [&](const f32x2 (&X)[8]) {
#pragma unroll
        for (int q = 0; q < 8; ++q) { ITER(X[q].x); ITER(X[q].y); }
    };

    f32x2 xA[8], xB[8];            // 32 VGPRs total, static indices only
    LOAD8(xA, 0);
    LOAD8(xB, 8);
    BLOCK16(xA);                   // iters  0..15
    LOAD8(xA, 16);                 // prefetch 32..47 (16-iter distance)
    BLOCK16(xB);                   // iters 16..31
    LOAD8(xB, 24);                 // prefetch 48..63
    BLOCK16(xA);                   // iters 32..47
    BLOCK16(xB);                   // iters 48..63

    if (!LAST) {
        ldsOut[rb + lane] = keepreg;            // single ds_write_b32, conflict-free
    } else {
        const int oi = t0 + lane - (K_LEN - 1); // coalesced chunk output, no staging
        if (oi >= 0 && oi < N_LEN) out[oi] = keepreg;
    }
}

__global__ __launch_bounds__(256, 1) void dtw_main(const float* __restrict__ xpad,
                                                   const float* __restrict__ kern,
                                                   float* __restrict__ out) {
    __shared__ float lds[4 * RING]; // buf[w]=w*RING for waves 0..2; INIT at 3*RING (wave0's in)
    const float INFV = __builtin_inff();
    const int tid  = threadIdx.x;
    const int w    = __builtin_amdgcn_readfirstlane(tid) >> 6; // wave id, uniform SGPR
    const int lane = tid & 63;

    // LDS init: all INF; INIT[255] = 0.0 is the DP seed ac[-1][-1]=0 (wave0, chunk0, r=0)
    for (int i = tid; i < 4 * RING; i += 256)
        lds[i] = (i == 4 * RING - 1) ? 0.0f : INFV;
    __syncthreads();

    const int j0 = w * 128 + 2 * lane;      // slot-0 column; slot-1 = j0+1
    const float k0 = kern[j0];
    const float k1 = kern[j0 + 1];

    // per-lane x stream: fresh (slot-0) x at diagonal t is xl[t]
    const float* xl = xpad + (PAD_L - j0);
    float xp = xl[-1];                      // slot-1 x entering t=0

    float* ldsOut      = lds + w * RING;    // wave3 never writes (LAST path)
    const float* ldsIn = (w == 0) ? (lds + 3 * RING) : (lds + (w - 1) * RING);

    float A0 = INFV, A0p = INFV, A1 = INFV, E1 = INFV;

    for (int S = 0; S < NCHUNK + 3; ++S) {
        const int c = S - w;                // chunk index for this wave (skewed pipeline)
        if (c >= 0 && c < NCHUNK) {
            if (w == 3)
                dtw_chunk<true>(c, xl, ldsIn, ldsOut, k0, k1, A0, A0p, A1, E1, xp, lane, out);
            else
                dtw_chunk<false>(c, xl, ldsIn, ldsOut, k0, k1, A0, A0p, A1, E1, xp, lane, out);
        }
        if (S == 0 && tid == 0) lds[4 * RING - 1] = INFV; // retire seed before ring wraps
        // LDS-only barrier: publish must drain (lgkmcnt), but wave3's global stores /
        // x loads need NOT (memory clobber pins the ds ops to this side of the barrier)
        asm volatile("s_waitcnt lgkmcnt(0)\n\ts_barrier" ::: "memory");
    }
}

extern "C" void kernel_launch(void* const* d_in, const int* in_sizes, int n_in,
                              void* d_out, int out_size, void* d_ws, size_t ws_size,
                              hipStream_t stream) {
    const float* x = (const float*)d_in[0];   // input, 65536 fp32
    const float* k = (const float*)d_in[1];   // kernel, 512 fp32
    float* xpad = (float*)d_ws;               // needs 268288 B of scratch
    float* out  = (float*)d_out;              // 65536 fp32
    dtw_pad_kernel<<<(XPAD_TOTAL + 255) / 256, 256, 0, stream>>>(x, xpad);
    dtw_main<<<1, 256, 0, stream>>>(xpad, k, out);
}